// Round 1
// baseline (76.888 us; speedup 1.0000x reference)
//
#include <hip/hip_runtime.h>

typedef _Float16 f16x8 __attribute__((ext_vector_type(8)));
typedef _Float16 f16x4 __attribute__((ext_vector_type(4)));
typedef float    f32x4 __attribute__((ext_vector_type(4)));

#define FDIM 64
#define EDIM 32
#define ADIM 4
// LDS strides in fp16 elements; all chosen so frag reads are 16B-aligned and
// near-conflict-free (per-16-lane bank analysis: 2-way max aliasing = free).
#define XH_S 56   // 112 B rows: bank start 28*i mod 32 -> 8 distinct groups
#define XT_S 72   // 144 B rows: bank start 4*e  mod 32 -> 8 distinct groups
#define P_S  72   // 144 B rows

__global__ __launch_bounds__(256, 4)
void afm_kernel(const float* __restrict__ x,
                const float* __restrict__ attn_w,
                const float* __restrict__ attn_b,
                const float* __restrict__ attn_h,
                const float* __restrict__ pool_w,
                const float* __restrict__ pool_b,
                float* __restrict__ out)
{
    __shared__ _Float16 Xh[FDIM * XH_S];   // x[i][e] fp16
    __shared__ _Float16 Xt[EDIM * XT_S];   // x[e][i] fp16 (transposed)
    __shared__ _Float16 Pm[FDIM * P_S];    // unnormalized attn exp, fp16
    __shared__ _Float16 Wh[ADIM * 32];     // w[a][e] fp16
    __shared__ float ldsmax[4];
    __shared__ float ldssum[4];
    __shared__ float redw[4][EDIM];

    const int tid  = threadIdx.x;
    const int bb   = blockIdx.x;
    const int wave = tid >> 6;
    const int lane = tid & 63;
    const int n16  = lane & 15;   // MFMA m/n index within 16-tile
    const int q    = lane >> 4;   // quad -> k-chunk / C-row group

    // ---- stage x -> Xh [i][e] and Xt [e][i], converting to fp16 ----
    const float* xb = x + (size_t)bb * (FDIM * EDIM);
    #pragma unroll
    for (int rep = 0; rep < 2; ++rep) {
        int idx4 = tid + rep * 256;        // 512 float4 = 64x32 floats
        int row  = idx4 >> 3;              // 8 float4 per row
        int c4   = idx4 & 7;
        float4 v = ((const float4*)xb)[idx4];
        _Float16 h0 = (_Float16)v.x, h1 = (_Float16)v.y,
                 h2 = (_Float16)v.z, h3 = (_Float16)v.w;
        f16x4 hv = {h0, h1, h2, h3};
        *(f16x4*)&Xh[row * XH_S + c4 * 4] = hv;
        int e0 = c4 * 4;
        Xt[(e0 + 0) * XT_S + row] = h0;
        Xt[(e0 + 1) * XT_S + row] = h1;
        Xt[(e0 + 2) * XT_S + row] = h2;
        Xt[(e0 + 3) * XT_S + row] = h3;
    }
    if (tid < ADIM * EDIM) {
        int a = tid & 3, e = tid >> 2;
        Wh[a * 32 + e] = (_Float16)attn_w[e * ADIM + a];
    }
    float hb[ADIM], hh[ADIM];
    #pragma unroll
    for (int a = 0; a < ADIM; ++a) { hb[a] = attn_b[a]; hh[a] = attn_h[a]; }
    __syncthreads();

    // ---- scores: dense[i,j,a] = sum_e (x[i,e]*w[e,a]) * x[j,e] via MFMA ----
    // A-frag: lane m = n16 (row i within band), k-chunk = q*8 (K=32 exactly)
    const int iA = wave * 16 + n16;
    f16x8 xafrag = *(const f16x8*)&Xh[iA * XH_S + q * 8];
    f16x8 bfrag[4];
    #pragma unroll
    for (int ct = 0; ct < 4; ++ct)   // B source: Xh[j][e], lane n = n16 -> j
        bfrag[ct] = *(const f16x8*)&Xh[(ct * 16 + n16) * XH_S + q * 8];

    float s[4][4];
    #pragma unroll
    for (int ct = 0; ct < 4; ++ct)
        #pragma unroll
        for (int r = 0; r < 4; ++r) s[ct][r] = 0.f;

    #pragma unroll
    for (int a = 0; a < ADIM; ++a) {
        f16x8 wfrag = *(const f16x8*)&Wh[a * 32 + q * 8];
        f16x8 ya = xafrag * wfrag;   // v_pk_mul_f16: A-operand = x_i * w_a
        #pragma unroll
        for (int ct = 0; ct < 4; ++ct) {
            f32x4 z = {0.f, 0.f, 0.f, 0.f};
            f32x4 acc = __builtin_amdgcn_mfma_f32_16x16x32_f16(ya, bfrag[ct], z, 0, 0, 0);
            #pragma unroll
            for (int r = 0; r < 4; ++r)
                s[ct][r] += fmaxf(acc[r] + hb[a], 0.f) * hh[a];
        }
    }

    // ---- masked (i<j) block softmax over all 2016 pairs ----
    // C layout: row = q*4 + r (within band), col = n16 (within col-tile)
    float mloc = -1e30f;
    #pragma unroll
    for (int ct = 0; ct < 4; ++ct)
        #pragma unroll
        for (int r = 0; r < 4; ++r) {
            int i = wave * 16 + q * 4 + r;
            int j = ct * 16 + n16;
            if (i < j) mloc = fmaxf(mloc, s[ct][r]);
        }
    #pragma unroll
    for (int off = 32; off >= 1; off >>= 1)
        mloc = fmaxf(mloc, __shfl_xor(mloc, off));
    if (lane == 0) ldsmax[wave] = mloc;
    __syncthreads();
    float M = fmaxf(fmaxf(ldsmax[0], ldsmax[1]), fmaxf(ldsmax[2], ldsmax[3]));

    float psum = 0.f;
    #pragma unroll
    for (int ct = 0; ct < 4; ++ct)
        #pragma unroll
        for (int r = 0; r < 4; ++r) {
            int i = wave * 16 + q * 4 + r;
            int j = ct * 16 + n16;
            float p = (i < j) ? __expf(s[ct][r] - M) : 0.f;
            psum += p;
            Pm[i * P_S + j] = (_Float16)p;   // unnormalized; /S deferred to end
        }
    #pragma unroll
    for (int off = 32; off >= 1; off >>= 1)
        psum += __shfl_xor(psum, off);
    if (lane == 0) ldssum[wave] = psum;
    __syncthreads();

    // ---- T = Pm @ X (64x32, K=64 -> 2 MFMAs), then reduced[e]=sum_i x[i,e]T[i,e]
    f16x8 pa0 = *(const f16x8*)&Pm[(wave * 16 + n16) * P_S + q * 8];
    f16x8 pa1 = *(const f16x8*)&Pm[(wave * 16 + n16) * P_S + 32 + q * 8];
    float tv[2];
    #pragma unroll
    for (int ctE = 0; ctE < 2; ++ctE) {
        // B source: Xt[e][j]; lane n = n16 -> e, k = j chunks
        f16x8 b0 = *(const f16x8*)&Xt[(ctE * 16 + n16) * XT_S + q * 8];
        f16x8 b1 = *(const f16x8*)&Xt[(ctE * 16 + n16) * XT_S + 32 + q * 8];
        f32x4 z = {0.f, 0.f, 0.f, 0.f};
        f32x4 acc = __builtin_amdgcn_mfma_f32_16x16x32_f16(pa0, b0, z, 0, 0, 0);
        acc = __builtin_amdgcn_mfma_f32_16x16x32_f16(pa1, b1, acc, 0, 0, 0);
        float t = 0.f;
        #pragma unroll
        for (int r = 0; r < 4; ++r) {
            int i = wave * 16 + q * 4 + r;
            int e = ctE * 16 + n16;
            t += acc[r] * (float)Xh[i * XH_S + e];
        }
        t += __shfl_xor(t, 16);   // sum over quads (rows of band)
        t += __shfl_xor(t, 32);
        tv[ctE] = t;
    }
    if (q == 0) {
        redw[wave][n16]      = tv[0];
        redw[wave][16 + n16] = tv[1];
    }
    __syncthreads();

    // ---- final: out[b] = (reduced . pool_w) / S + pool_b ----
    if (tid < EDIM) {
        float S = ldssum[0] + ldssum[1] + ldssum[2] + ldssum[3];
        float v = (redw[0][tid] + redw[1][tid] + redw[2][tid] + redw[3][tid]) * pool_w[tid];
        #pragma unroll
        for (int off = 16; off >= 1; off >>= 1)
            v += __shfl_xor(v, off);
        if (tid == 0) out[bb] = v / S + pool_b[0];
    }
}

extern "C" void kernel_launch(void* const* d_in, const int* in_sizes, int n_in,
                              void* d_out, int out_size, void* d_ws, size_t ws_size,
                              hipStream_t stream) {
    const float* x      = (const float*)d_in[0];
    const float* attn_w = (const float*)d_in[1];
    const float* attn_b = (const float*)d_in[2];
    const float* attn_h = (const float*)d_in[3];
    const float* pool_w = (const float*)d_in[4];
    const float* pool_b = (const float*)d_in[5];
    float* out = (float*)d_out;
    int B = in_sizes[0] / (FDIM * EDIM);
    afm_kernel<<<B, 256, 0, stream>>>(x, attn_w, attn_b, attn_h, pool_w, pool_b, out);
}

// Round 2
// 76.282 us; speedup vs baseline: 1.0079x; 1.0079x over previous
//
#include <hip/hip_runtime.h>

typedef _Float16 f16x8 __attribute__((ext_vector_type(8)));
typedef _Float16 f16x4 __attribute__((ext_vector_type(4)));
typedef float    f32x4 __attribute__((ext_vector_type(4)));

#define FDIM 64
#define EDIM 32
#define ADIM 4
#define XH_S 40   // halves; rows 80B -> bank starts 20*i mod 32, 2-way max = free

// tile linearization: tiles (mt, nt) with nt >= mt; base offset per mt
__device__ __constant__ int TBASE_host_unused[4] = {0, 4, 7, 9};

__global__ __launch_bounds__(256, 3)
void afm_kernel(const float* __restrict__ x,
                const float* __restrict__ attn_w,
                const float* __restrict__ attn_b,
                const float* __restrict__ attn_h,
                const float* __restrict__ pool_w,
                const float* __restrict__ pool_b,
                float* __restrict__ out)
{
    __shared__ _Float16 Xh[4][FDIM * XH_S];  // per-wave x slab, fp16 [i][e]
    __shared__ _Float16 Wh[ADIM * EDIM];     // w[a][e] fp16
    __shared__ _Float16 Pwh[EDIM];           // pool_w fp16

    const int tid  = threadIdx.x;
    const int wave = tid >> 6;
    const int lane = tid & 63;
    const int n16  = lane & 15;   // MFMA m/n index within 16-tile
    const int q    = lane >> 4;   // quad -> k-chunk / C-row group

    const int batch = blockIdx.x * 4 + wave;
    const float* xb = x + (size_t)batch * (FDIM * EDIM);
    _Float16* xh = Xh[wave];

    // ---- stage this wave's x -> fp16 LDS [i][e], coalesced float4 ----
    #pragma unroll
    for (int k = 0; k < 8; ++k) {
        int idx = lane + 64 * k;          // 512 float4 = 64x32 floats
        float4 v = ((const float4*)xb)[idx];
        int row = idx >> 3, c4 = idx & 7;
        f16x4 hv = {(_Float16)v.x, (_Float16)v.y, (_Float16)v.z, (_Float16)v.w};
        *(f16x4*)&xh[row * XH_S + c4 * 4] = hv;
    }
    if (tid < ADIM * EDIM) {              // stage attn_w transposed -> [a][e]
        int a = tid >> 5, e = tid & 31;
        Wh[a * EDIM + e] = (_Float16)attn_w[e * ADIM + a];
    } else if (tid < ADIM * EDIM + EDIM) {
        int e = tid - ADIM * EDIM;
        Pwh[e] = (_Float16)pool_w[e];
    }
    float hb[ADIM], hh[ADIM];
    #pragma unroll
    for (int a = 0; a < ADIM; ++a) { hb[a] = attn_b[a]; hh[a] = attn_h[a]; }
    __syncthreads();   // the ONLY block barrier (Wh/Pwh shared across waves)

    // ---- fragments ----
    f16x8 bfrag[4], wfrag[4];
    #pragma unroll
    for (int ct = 0; ct < 4; ++ct)
        bfrag[ct] = *(const f16x8*)&xh[(ct * 16 + n16) * XH_S + q * 8];
    #pragma unroll
    for (int a = 0; a < ADIM; ++a)
        wfrag[a] = *(const f16x8*)&Wh[a * EDIM + q * 8];
    f16x8 pwf = *(const f16x8*)&Pwh[q * 8];

    // ---- scores on upper-triangular tiles only: 10 tiles x 4 a = 40 MFMAs ----
    // s[i,j] = sum_a h_a * relu( sum_e (x_i,e w_e,a) x_j,e + b_a )
    float val[10][4];
    #pragma unroll
    for (int t = 0; t < 10; ++t)
        #pragma unroll
        for (int r = 0; r < 4; ++r) val[t][r] = 0.f;

    const int tbase[4] = {0, 4, 7, 9};
    #pragma unroll
    for (int mt = 0; mt < 4; ++mt) {
        f16x8 xa = *(const f16x8*)&xh[(mt * 16 + n16) * XH_S + q * 8];
        #pragma unroll
        for (int a = 0; a < ADIM; ++a) {
            f16x8 ya = xa * wfrag[a];      // v_pk_mul_f16: A-operand = x_i * w_a
            #pragma unroll
            for (int nt = mt; nt < 4; ++nt) {
                f32x4 z = {0.f, 0.f, 0.f, 0.f};
                f32x4 acc = __builtin_amdgcn_mfma_f32_16x16x32_f16(ya, bfrag[nt], z, 0, 0, 0);
                int t = tbase[mt] + (nt - mt);
                #pragma unroll
                for (int r = 0; r < 4; ++r)
                    val[t][r] += fmaxf(acc[r] + hb[a], 0.f) * hh[a];
            }
        }
    }

    // ---- wave-local masked softmax over 2016 pairs (i<j) ----
    // C layout: row i = mt*16 + q*4 + r, col j = nt*16 + n16
    float M = -3e38f;
    #pragma unroll
    for (int mt = 0; mt < 4; ++mt)
        #pragma unroll
        for (int nt = mt; nt < 4; ++nt) {
            int t = tbase[mt] + (nt - mt);
            #pragma unroll
            for (int r = 0; r < 4; ++r) {
                bool valid = (nt > mt) || ((q * 4 + r) < n16);
                if (valid) M = fmaxf(M, val[t][r]);
            }
        }
    #pragma unroll
    for (int off = 32; off >= 1; off >>= 1)
        M = fmaxf(M, __shfl_xor(M, off));

    float psum = 0.f;
    #pragma unroll
    for (int mt = 0; mt < 4; ++mt)
        #pragma unroll
        for (int nt = mt; nt < 4; ++nt) {
            int t = tbase[mt] + (nt - mt);
            #pragma unroll
            for (int r = 0; r < 4; ++r) {
                bool valid = (nt > mt) || ((q * 4 + r) < n16);
                float p = valid ? __expf(val[t][r] - M) : 0.f;
                val[t][r] = p;            // overwrite scores with unnormalized probs
                psum += p;
            }
        }

    // ---- G = X diag(pool_w) X^T on the same tiles; dot with P in-register ----
    float dot = 0.f;
    #pragma unroll
    for (int mt = 0; mt < 4; ++mt) {
        f16x8 xa = *(const f16x8*)&xh[(mt * 16 + n16) * XH_S + q * 8];
        f16x8 yp = xa * pwf;               // x_i * pool_w (elementwise over e)
        #pragma unroll
        for (int nt = mt; nt < 4; ++nt) {
            f32x4 z = {0.f, 0.f, 0.f, 0.f};
            f32x4 g = __builtin_amdgcn_mfma_f32_16x16x32_f16(yp, bfrag[nt], z, 0, 0, 0);
            int t = tbase[mt] + (nt - mt);
            #pragma unroll
            for (int r = 0; r < 4; ++r)
                dot += val[t][r] * g[r];   // masked entries have p=0
        }
    }

    // ---- reduce {dot, psum} across the wave; one store per batch ----
    #pragma unroll
    for (int off = 32; off >= 1; off >>= 1) {
        dot  += __shfl_xor(dot, off);
        psum += __shfl_xor(psum, off);
    }
    if (lane == 0)
        out[batch] = dot / psum + pool_b[0];
}

extern "C" void kernel_launch(void* const* d_in, const int* in_sizes, int n_in,
                              void* d_out, int out_size, void* d_ws, size_t ws_size,
                              hipStream_t stream) {
    const float* x      = (const float*)d_in[0];
    const float* attn_w = (const float*)d_in[1];
    const float* attn_b = (const float*)d_in[2];
    const float* attn_h = (const float*)d_in[3];
    const float* pool_w = (const float*)d_in[4];
    const float* pool_b = (const float*)d_in[5];
    float* out = (float*)d_out;
    int B = in_sizes[0] / (FDIM * EDIM);
    afm_kernel<<<B / 4, 256, 0, stream>>>(x, attn_w, attn_b, attn_h, pool_w, pool_b, out);
}